// Round 7
// baseline (213.235 us; speedup 1.0000x reference)
//
#include <hip/hip_runtime.h>
#include <hip/hip_bf16.h>

#define B_ 32
#define N_ 512
#define H_ 128

typedef float f32x4 __attribute__((ext_vector_type(4)));
typedef short short8 __attribute__((ext_vector_type(8)));
typedef short short4v __attribute__((ext_vector_type(4)));

static __device__ __forceinline__ float bf2f(unsigned short u) {
  union { unsigned int ui; float f; } x;
  x.ui = ((unsigned int)u) << 16;
  return x.f;
}
static __device__ __forceinline__ unsigned short f2bf(float f) {
  __hip_bfloat16 h = __float2bfloat16(f);
  return *reinterpret_cast<unsigned short*>(&h);
}

// -------------------------------------------------------------------------
// Kernel 1: h[b,n,d] = silu(LN(s[b,n,:] @ W1[d,:] + b1[d]))
// stored TRANSPOSED bf16 into ws:  h_t[b][d][n]
// (unchanged — not the bottleneck per rocprof)
// -------------------------------------------------------------------------
__global__ __launch_bounds__(256) void lin_ln_silu_kernel(
    const float* __restrict__ s, const float* __restrict__ W1,
    const float* __restrict__ b1, unsigned short* __restrict__ h_t) {
  __shared__ float s_sh[32 * 132];            // [n][k] fp32, pad 132
  __shared__ unsigned short w_sh[128 * 132];  // [d][k] bf16, pad 132
  __shared__ unsigned short ht_sh[128 * 40];  // [d][n] bf16, pad 40
  const int t = threadIdx.x;
  const int b = blockIdx.y;
  const int n0 = blockIdx.x * 32;

#pragma unroll
  for (int r = 0; r < 16; ++r) {
    int q = t + 256 * r;
    int d = q >> 5, part = q & 31;
    float4 v = *reinterpret_cast<const float4*>(W1 + d * H_ + part * 4);
    short4v w;
    w.x = (short)f2bf(v.x); w.y = (short)f2bf(v.y);
    w.z = (short)f2bf(v.z); w.w = (short)f2bf(v.w);
    *reinterpret_cast<short4v*>(&w_sh[d * 132 + part * 4]) = w;
  }
#pragma unroll
  for (int r = 0; r < 4; ++r) {
    int q = t + 256 * r;
    int n = q >> 5, part = q & 31;
    float4 v = *reinterpret_cast<const float4*>(
        s + ((size_t)b * N_ + n0 + n) * H_ + part * 4);
    *reinterpret_cast<float4*>(&s_sh[n * 132 + part * 4]) = v;
  }
  __syncthreads();

  const int a = t & 15;
  const int g = t >> 4;
  float acc[2][8];
#pragma unroll
  for (int nn = 0; nn < 2; ++nn)
#pragma unroll
    for (int dd = 0; dd < 8; ++dd) acc[nn][dd] = 0.f;

  float bias[8];
#pragma unroll
  for (int dd = 0; dd < 8; ++dd) bias[dd] = b1[dd * 16 + a];

  for (int k = 0; k < 128; k += 4) {
    float wf[8][4];
#pragma unroll
    for (int dd = 0; dd < 8; ++dd) {
      short4v wv =
          *reinterpret_cast<const short4v*>(&w_sh[(dd * 16 + a) * 132 + k]);
      wf[dd][0] = bf2f((unsigned short)wv.x);
      wf[dd][1] = bf2f((unsigned short)wv.y);
      wf[dd][2] = bf2f((unsigned short)wv.z);
      wf[dd][3] = bf2f((unsigned short)wv.w);
    }
#pragma unroll
    for (int nn = 0; nn < 2; ++nn) {
      float4 sv =
          *reinterpret_cast<const float4*>(&s_sh[(nn * 16 + g) * 132 + k]);
#pragma unroll
      for (int dd = 0; dd < 8; ++dd) {
        acc[nn][dd] += sv.x * wf[dd][0] + sv.y * wf[dd][1] +
                       sv.z * wf[dd][2] + sv.w * wf[dd][3];
      }
    }
  }

#pragma unroll
  for (int nn = 0; nn < 2; ++nn) {
    float s1 = 0.f, s2 = 0.f;
#pragma unroll
    for (int dd = 0; dd < 8; ++dd) {
      float x = acc[nn][dd] + bias[dd];
      acc[nn][dd] = x;
      s1 += x;
      s2 += x * x;
    }
#pragma unroll
    for (int off = 8; off >= 1; off >>= 1) {
      s1 += __shfl_xor(s1, off);
      s2 += __shfl_xor(s2, off);
    }
    float mean = s1 * (1.f / 128.f);
    float var = s2 * (1.f / 128.f) - mean * mean;
    float rs = rsqrtf(var + 1e-5f);
#pragma unroll
    for (int dd = 0; dd < 8; ++dd) {
      float x = (acc[nn][dd] - mean) * rs;
      float y = x / (1.f + __expf(-x));  // silu
      ht_sh[(dd * 16 + a) * 40 + nn * 16 + g] = f2bf(y);
    }
  }
  __syncthreads();

#pragma unroll
  for (int r = 0; r < 2; ++r) {
    int q = t + 256 * r;
    int d = q >> 2, part = q & 3;
    float4 v = *reinterpret_cast<const float4*>(&ht_sh[d * 40 + part * 8]);
    *reinterpret_cast<float4*>(
        h_t + ((size_t)b * 128 + d) * 512 + n0 + part * 8) = v;
  }
}

// -------------------------------------------------------------------------
// Kernel 2, round 7: BARRIER-FREE free-running waves + h-resident LDS.
// v[b,i,c,d] = sum_j mask[b,i,j]*ev[b,i,j,c]*h[b,j,d].
//
// R0-R6 all landed 61-67us across every staging/pipelining variant; the
// shared invariant was 8 rounds x 3-4 block-wide barriers with ~300cy of
// compute between them -> all resident waves convoy at the syncs and the
// machine runs at rounds x latency. This round removes the rounds:
//  - Block = (b, 64 i). h_t[b] (128KB = full K) staged into LDS ONCE
//    (XOR-swizzled 16B chunks at ds_write; read-side matches -> b128
//    reads at the 8-phase minimum, conflict-free). ONE barrier total.
//  - Each wave owns 16 i x 128 d and free-runs 8 j-steps with NO
//    inter-wave sync: per-lane ev/mask loads (lane = its A-fragment row;
//    96B contiguous runs, 16 dwordx4/step) asm-pinned at distance 2 with
//    counted vmcnt(16). A-fragments built in registers (no ph LDS).
//  - Little's law: 32KB in flight/wave x 4 waves = 128KB/CU >> the
//    ~15KB needed to sustain 10.25 B/cy/CU -> latency self-hidden even
//    at 1 wave/SIMD.
// Floor: ev+mask 134MB unique HBM ~= 21us.
// Grid: (N/64, B) = (8,32) = 256 blocks, 256 thr, 1 block/CU.
// -------------------------------------------------------------------------
__global__ __launch_bounds__(256, 1) void cfconv_mfma_kernel(
    const float* __restrict__ ev, const float* __restrict__ mask,
    const unsigned short* __restrict__ h_t, float* __restrict__ out) {
  __shared__ unsigned short hL[128 * 512];  // 128 KiB: h_t[b], swizzled
  const int t = threadIdx.x;
  const int b = blockIdx.y;
  const int i0 = blockIdx.x * 64;
  const int w = t >> 6, l = t & 63;
  const int l15 = l & 15, quad = l >> 4;
  const int ig = i0 + w * 16 + l15;  // this lane's i row (A operand)

  // ---- prologue: stage h_t[b] (128 rows x 1KB) into LDS, swizzled ----
  // wave w stages rows [w*32, w*32+32). lane l: 16B chunk; window=l>>3
  // (128B), chunk-in-window=(l&7) stored at (l&7)^(row&7).
  {
    const unsigned short* hb = h_t + (size_t)b * 65536;
#pragma unroll 4
    for (int r2 = 0; r2 < 32; ++r2) {
      int row = w * 32 + r2;
      float4 v = *reinterpret_cast<const float4*>(hb + row * 512 + l * 8);
      *reinterpret_cast<float4*>(
          &hL[row * 512 + (l >> 3) * 64 + (((l & 7) ^ (row & 7)) * 8)]) = v;
    }
  }
  __syncthreads();  // the ONLY barrier

  f32x4 acc[3][8];
#pragma unroll
  for (int mt = 0; mt < 3; ++mt)
#pragma unroll
    for (int nt = 0; nt < 8; ++nt)
#pragma unroll
      for (int e = 0; e < 4; ++e) acc[mt][nt][e] = 0.f;

  // per-lane stream bases: this lane's A-row (i=ig), j base = quad*8
  const float* evrow =
      ev + ((size_t)(b * N_) + ig) * (N_ * 3) + quad * 24;
  const float* mrow = mask + ((size_t)(b * N_) + ig) * N_ + quad * 8;

  // distance-2 prefetch sets (asm-pinned): 12 ev + 4 mask dwordx4 each
  f32x4 evA[12], mkA[4], evB[12], mkB[4];
  short8 av[3][2];

#define ALOADO(DST, PTR, OFF)                                    \
  asm volatile("global_load_dwordx4 %0, %1, off offset:" OFF     \
               : "=v"(DST) : "v"(PTR))

// per j-step, this lane needs ev[(ig), j=q*8+ks*32+e, c] (24 floats/ks,
// contiguous 96B) and mask[(ig), same 8 j] (32B/ks).
#define ISSUE_SET(EVX, MKX, R)                                   \
  do {                                                           \
    const char* ep_ = (const char*)evrow + (R)*768;              \
    const char* mp_ = (const char*)mrow + (R)*256;               \
    ALOADO(EVX[0], ep_, "0");    ALOADO(EVX[1], ep_, "16");      \
    ALOADO(EVX[2], ep_, "32");   ALOADO(EVX[3], ep_, "48");      \
    ALOADO(EVX[4], ep_, "64");   ALOADO(EVX[5], ep_, "80");      \
    ALOADO(EVX[6], ep_, "384");  ALOADO(EVX[7], ep_, "400");     \
    ALOADO(EVX[8], ep_, "416");  ALOADO(EVX[9], ep_, "432");     \
    ALOADO(EVX[10], ep_, "448"); ALOADO(EVX[11], ep_, "464");    \
    ALOADO(MKX[0], mp_, "0");    ALOADO(MKX[1], mp_, "16");      \
    ALOADO(MKX[2], mp_, "128");  ALOADO(MKX[3], mp_, "144");     \
  } while (0)

// counted vmem wait + compile-time fence (keeps CONV after the wait;
// the compiler does NOT track inline-asm load results itself)
#define VMW(n)                                       \
  do {                                               \
    asm volatile("s_waitcnt vmcnt(" #n ")");         \
    __builtin_amdgcn_sched_barrier(0);               \
  } while (0)

// build av[c][ks] (short8, 8 consecutive j) = bf16(ev*mask) from a set
#define CONV(EVX, MKX)                                                  \
  do {                                                                  \
    _Pragma("unroll") for (int ks_ = 0; ks_ < 2; ++ks_) {               \
      float p_[8][3];                                                   \
      _Pragma("unroll") for (int e_ = 0; e_ < 8; ++e_) {                \
        float mv_ = MKX[ks_ * 2 + (e_ >> 2)][e_ & 3];                   \
        _Pragma("unroll") for (int c_ = 0; c_ < 3; ++c_) {              \
          int f_ = e_ * 3 + c_;                                         \
          p_[e_][c_] = EVX[ks_ * 6 + (f_ >> 2)][f_ & 3] * mv_;          \
        }                                                               \
      }                                                                 \
      _Pragma("unroll") for (int c_ = 0; c_ < 3; ++c_) {                \
        short8 a_;                                                      \
        _Pragma("unroll") for (int e_ = 0; e_ < 8; ++e_)                \
            a_[e_] = (short)f2bf(p_[e_][c_]);                           \
        av[c_][ks_] = a_;                                               \
      }                                                                 \
    }                                                                   \
  } while (0)

// J0 in ushort units (= jstep*64). bv read uses the matching chunk
// swizzle: true chunk (ks*4+quad) stored at ^(d&7), d&7 == l15&7.
#define COMPUTE(J0)                                                     \
  do {                                                                  \
    _Pragma("unroll") for (int ks_ = 0; ks_ < 2; ++ks_) {               \
      _Pragma("unroll") for (int nt_ = 0; nt_ < 8; ++nt_) {             \
        int d_ = nt_ * 16 + l15;                                        \
        short8 bv_ = *reinterpret_cast<const short8*>(                  \
            &hL[d_ * 512 + (J0) +                                       \
                (((ks_ * 4 + quad) ^ (l15 & 7)) * 8)]);                 \
        _Pragma("unroll") for (int mt_ = 0; mt_ < 3; ++mt_)             \
            acc[mt_][nt_] = __builtin_amdgcn_mfma_f32_16x16x32_bf16(    \
                av[mt_][ks_], bv_, acc[mt_][nt_], 0, 0, 0);             \
      }                                                                 \
    }                                                                   \
  } while (0)

  // ---- free-running pipeline: no barriers, counted waits only ----
  ISSUE_SET(evA, mkA, 0);
  ISSUE_SET(evB, mkB, 1);

  VMW(16); CONV(evA, mkA); ISSUE_SET(evA, mkA, 2); COMPUTE(0);
  VMW(16); CONV(evB, mkB); ISSUE_SET(evB, mkB, 3); COMPUTE(64);
  VMW(16); CONV(evA, mkA); ISSUE_SET(evA, mkA, 4); COMPUTE(128);
  VMW(16); CONV(evB, mkB); ISSUE_SET(evB, mkB, 5); COMPUTE(192);
  VMW(16); CONV(evA, mkA); ISSUE_SET(evA, mkA, 6); COMPUTE(256);
  VMW(16); CONV(evB, mkB); ISSUE_SET(evB, mkB, 7); COMPUTE(320);
  VMW(16); CONV(evA, mkA); COMPUTE(384);
  VMW(0);  CONV(evB, mkB); COMPUTE(448);

#undef COMPUTE
#undef CONV
#undef VMW
#undef ISSUE_SET
#undef ALOADO

  // epilogue: C/D layout col=lane&15 (d), row=quad*4+reg (i-local); c=mt
#pragma unroll
  for (int mt = 0; mt < 3; ++mt) {
#pragma unroll
    for (int nt = 0; nt < 8; ++nt) {
      int d = nt * 16 + l15;
#pragma unroll
      for (int r = 0; r < 4; ++r) {
        int i = i0 + w * 16 + quad * 4 + r;
        out[(((size_t)b * N_ + i) * 3 + mt) * H_ + d] = acc[mt][nt][r];
      }
    }
  }
}

extern "C" void kernel_launch(void* const* d_in, const int* in_sizes, int n_in,
                              void* d_out, int out_size, void* d_ws,
                              size_t ws_size, hipStream_t stream) {
  const float* s = (const float*)d_in[0];
  const float* ev = (const float*)d_in[1];
  const float* mask = (const float*)d_in[2];
  const float* W1 = (const float*)d_in[3];
  const float* b1 = (const float*)d_in[4];
  float* out = (float*)d_out;
  // ws: h_t bf16 [B][128 d][512 n] = 4 MB
  unsigned short* h_t = (unsigned short*)d_ws;

  lin_ln_silu_kernel<<<dim3(N_ / 32, B_), 256, 0, stream>>>(s, W1, b1, h_t);
  cfconv_mfma_kernel<<<dim3(N_ / 64, B_), 256, 0, stream>>>(ev, mask, h_t, out);
}